// Round 11
// baseline (91.287 us; speedup 1.0000x reference)
//
#include <hip/hip_runtime.h>
#include <hip/hip_bf16.h>
#include <math.h>

#define BB 32
#define TTOT 1024
#define KK 16
#define DD 80
#define PP 64

// workspace layout (float offsets)
#define WS_DCONST 128      // 512 = B*K
#define WS_CVEC   1024     // 512*80 -> ends 41984
#define WS_PART2  41984    // 2048 (k2 per-block partials) -> 44032
#define WS_PART3L 44032    // 1600 (k3_lreg per-block partials) -> 45632
#define WS_PART3M 45632    // 64 (k3_mureg per-block partials) -> 45696
#define WS_XBF16  46080    // bf16[32*1024*80] = 1,310,720 floats -> ends 1,356,800
#define WS_MINVB  1356800  // bf16[512*80*80]  = 1,638,400 floats -> ends 2,995,200 (12.0 MB)

typedef short bf16x8 __attribute__((ext_vector_type(8)));
typedef float f32x4 __attribute__((ext_vector_type(4)));

__device__ __forceinline__ float wave_sum(float v) {
#pragma unroll
  for (int o = 32; o > 0; o >>= 1) v += __shfl_down(v, o);
  return v;
}

__device__ __forceinline__ unsigned short f2bf(float f) {
  __hip_bfloat16 h = __float2bfloat16(f);
  return *reinterpret_cast<unsigned short*>(&h);
}

// ---- KX: x fp32 -> bf16 (same layout) ----
__global__ __launch_bounds__(256) void kx_cast(const float* __restrict__ x,
                                               float* __restrict__ ws) {
  size_t idx = (size_t)blockIdx.x * 256 + threadIdx.x;  // one per 4 floats
  float4 v = reinterpret_cast<const float4*>(x)[idx];
  uint2 o;
  o.x = ((unsigned)f2bf(v.y) << 16) | f2bf(v.x);
  o.y = ((unsigned)f2bf(v.w) << 16) | f2bf(v.z);
  reinterpret_cast<uint2*>((__hip_bfloat16*)(ws + WS_XBF16))[idx] = o;
}

// ---- K1: per (b,k) triangular inverse; emit Minv as bf16, c fp32, dconst ----
// R9 lesson: L is block-uniform -> read it on the SCALAR pipe (s_load via a
// readfirstlane-pinned pointer), not LDS (R9: 640 uniform ds_read_b128/wave
// saturated the shared LDS pipe) and not per-lane global (R8: latency-exposed
// at 4 waves/CU). LDS holds only ys (each thread's own solution column).
// Per-thread arrays stay 16-wide, statically indexed (no scratch).
__global__ __launch_bounds__(128, 1) void k1_inv(const float* __restrict__ L_subj,
                                                 const float* __restrict__ mu_subj,
                                                 const int* __restrict__ sids,
                                                 float* __restrict__ ws) {
  int k = blockIdx.x, b = blockIdx.y;
  int p = __builtin_amdgcn_readfirstlane(sids[b]);
  const float* Lg = L_subj + ((size_t)(p * KK + k)) * DD * DD;   // uniform -> s_load
  const float* mug = mu_subj + (size_t)(p * KK + k) * DD;
  int bk = b * KK + k;

  __shared__ float ys[DD * 81 + 64];   // Minv (fp32), stride 81; +64 OOB pad
  __shared__ float rdiag[DD];
  __shared__ float lgd[DD];

  int tid = threadIdx.x;
  if (tid < DD) {
    float dv = Lg[tid * DD + tid];
    rdiag[tid] = 1.0f / dv;
    lgd[tid] = logf(dv);
  }
  __syncthreads();

  const int j = tid;  // column of Minv this thread solves: L y = e_j
  const bool act = j < DD;
  for (int ci = 0; ci < 5; ++ci) {
    const int r0 = ci * 16;
    float s[16];
#pragma unroll
    for (int ii = 0; ii < 16; ++ii) s[ii] = (r0 + ii == j) ? 1.0f : 0.0f;
    // cross-chunk contributions: L via uniform s_load float4, ym stride-1 LDS
    for (int cp = 0; cp < ci; ++cp) {
      float ym[16];
#pragma unroll
      for (int m = 0; m < 16; ++m) ym[m] = ys[(cp * 16 + m) * 81 + j];
#pragma unroll
      for (int ii = 0; ii < 16; ++ii) {
        const float4* Lr = reinterpret_cast<const float4*>(&Lg[(r0 + ii) * DD + cp * 16]);
        float4 a0 = Lr[0], a1 = Lr[1], a2 = Lr[2], a3 = Lr[3];
        float t = s[ii];
        t = fmaf(-a0.x, ym[0], t);  t = fmaf(-a0.y, ym[1], t);
        t = fmaf(-a0.z, ym[2], t);  t = fmaf(-a0.w, ym[3], t);
        t = fmaf(-a1.x, ym[4], t);  t = fmaf(-a1.y, ym[5], t);
        t = fmaf(-a1.z, ym[6], t);  t = fmaf(-a1.w, ym[7], t);
        t = fmaf(-a2.x, ym[8], t);  t = fmaf(-a2.y, ym[9], t);
        t = fmaf(-a2.z, ym[10], t); t = fmaf(-a2.w, ym[11], t);
        t = fmaf(-a3.x, ym[12], t); t = fmaf(-a3.y, ym[13], t);
        t = fmaf(-a3.z, ym[14], t); t = fmaf(-a3.w, ym[15], t);
        s[ii] = t;
      }
    }
    // in-chunk 16x16 triangular solve; L reads are uniform s_loads
    float yc[16];
#pragma unroll
    for (int ii = 0; ii < 16; ++ii) {
      float v = s[ii];
#pragma unroll
      for (int mm = 0; mm < 16; ++mm)
        if (mm < ii) v = fmaf(-Lg[(r0 + ii) * DD + r0 + mm], yc[mm], v);
      yc[ii] = v * rdiag[r0 + ii];
    }
    if (act) {
#pragma unroll
      for (int ii = 0; ii < 16; ++ii) ys[(r0 + ii) * 81 + j] = yc[ii];
    }
  }
  __syncthreads();

  // coalesced bf16 write of Minv rows (2 bf16 per uint)
  unsigned* Mg = reinterpret_cast<unsigned*>(
      (__hip_bfloat16*)(ws + WS_MINVB) + (size_t)bk * DD * DD);
  for (int idx = tid; idx < DD * (DD / 2); idx += 128) {
    int i = idx / (DD / 2), jp = idx % (DD / 2);
    unsigned u = ((unsigned)f2bf(ys[i * 81 + 2 * jp + 1]) << 16) | f2bf(ys[i * 81 + 2 * jp]);
    Mg[idx] = u;
  }

  if (tid < DD) {
    int i = tid;
    float ci = 0.f;
#pragma unroll 8
    for (int jj = 0; jj < DD; ++jj) ci = fmaf(ys[i * 81 + jj], mug[jj], ci);
    ws[WS_CVEC + bk * DD + i] = ci;
  }
  if (tid == 0) {
    float s = 0.f;
    for (int i = 0; i < DD; ++i) s += lgd[i];
    ws[WS_DCONST + bk] = (float)(0.5 * 80.0 * 1.8378770664093453) + s;  // 0.5*D*ln(2pi)+logdet
  }
}

// ---- K2: MFMA main loss. Block = (k, ttile of 256, b); 4 waves x 64 t. ----
// Writes ONE partial per block (no global atomics).
__global__ __launch_bounds__(256) void k2_mfma(const float* __restrict__ gamma,
                                               const float* __restrict__ ws,
                                               float* __restrict__ part) {
  const int k = blockIdx.x, tt = blockIdx.y, b = blockIdx.z;
  const int w = threadIdx.x >> 6, l = threadIdx.x & 63;
  const int lg = l >> 4, lr = l & 15;
  const int bk = b * KK + k;

  const __hip_bfloat16* Xb = (const __hip_bfloat16*)(ws + WS_XBF16) + (size_t)b * TTOT * DD;
  const __hip_bfloat16* Mb = (const __hip_bfloat16*)(ws + WS_MINVB) + (size_t)bk * DD * DD;
  const float* cc = ws + WS_CVEC + bk * DD;
  const float dconst = ws[WS_DCONST + bk];

  const int t0 = tt * 256 + w * 64;  // wave's t base

  f32x4 accf[5][4] = {};  // [m-tile][n-frag]
#pragma unroll
  for (int c = 0; c < 3; ++c) {
    const int j = c * 32 + lg * 8;
    const bool dead = (c == 2) && (lg >= 2);  // j >= 80: zero-pad K to 96
    bf16x8 af[5], bf[4];
#pragma unroll
    for (int mt = 0; mt < 5; ++mt)
      af[mt] = dead ? (bf16x8){} : *(const bf16x8*)(Mb + (mt * 16 + lr) * DD + j);
#pragma unroll
    for (int nf = 0; nf < 4; ++nf)
      bf[nf] = dead ? (bf16x8){} : *(const bf16x8*)(Xb + (size_t)(t0 + nf * 16 + lr) * DD + j);
#pragma unroll
    for (int mt = 0; mt < 5; ++mt)
#pragma unroll
      for (int nf = 0; nf < 4; ++nf)
        accf[mt][nf] = __builtin_amdgcn_mfma_f32_16x16x32_bf16(af[mt], bf[nf], accf[mt][nf], 0, 0, 0);
  }

  // epilogue: maha per t, gamma-weighted accumulate
  float c_r[5][4];
#pragma unroll
  for (int mt = 0; mt < 5; ++mt)
#pragma unroll
    for (int r = 0; r < 4; ++r)
      c_r[mt][r] = cc[mt * 16 + lg * 4 + r];  // row i = mt*16 + lg*4 + r

  float v = 0.f;
#pragma unroll
  for (int nf = 0; nf < 4; ++nf) {
    float s = 0.f;
#pragma unroll
    for (int mt = 0; mt < 5; ++mt)
#pragma unroll
      for (int r = 0; r < 4; ++r) {
        float z = accf[mt][nf][r] - c_r[mt][r];
        s = fmaf(z, z, s);
      }
    s += __shfl_xor(s, 16);
    s += __shfl_xor(s, 32);  // all 4 lane-groups combined: full maha for col lr
    float g = 0.f;
    int t = t0 + nf * 16 + lr;
    if (l < 16) g = gamma[((size_t)b * TTOT + t) * KK + k];
    v = fmaf(g, dconst + 0.5f * s, v);
  }
  v = wave_sum(v);

  __shared__ float red[4];
  if (l == 0) red[w] = v;
  __syncthreads();
  if (threadIdx.x == 0)
    part[(b * 4 + tt) * KK + k] = red[0] + red[1] + red[2] + red[3];
}

// ---- K3: L regularizer; mask recomputed from sids (k0 eliminated) ----
__global__ __launch_bounds__(256) void k3_lreg(const float* __restrict__ L_subj,
                                               const float* __restrict__ L_pop,
                                               const int* __restrict__ sids,
                                               float* __restrict__ part) {
  int p = blockIdx.y;
  int chunk = blockIdx.x;  // 25 chunks x 1024 float4 per subject
  int pidx = p * 25 + chunk;
  int found = 0;
  for (int b2 = 0; b2 < BB; ++b2) found |= (sids[b2] == p) ? 1 : 0;
  if (!found) {
    if (threadIdx.x == 0) part[pidx] = 0.f;
    return;
  }
  const float4* a4 = reinterpret_cast<const float4*>(L_subj) + (size_t)p * (KK * DD * DD / 4);
  const float4* b4 = reinterpret_cast<const float4*>(L_pop);
  float s = 0.f;
#pragma unroll
  for (int q = 0; q < 4; ++q) {
    int o = chunk * 1024 + q * 256 + threadIdx.x;
    float4 a = a4[o], bb = b4[o];
    float d0 = a.x - bb.x, d1 = a.y - bb.y, d2 = a.z - bb.z, d3 = a.w - bb.w;
    s += d0 * d0 + d1 * d1 + d2 * d2 + d3 * d3;
  }
  s = wave_sum(s);
  __shared__ float red[4];
  if ((threadIdx.x & 63) == 0) red[threadIdx.x >> 6] = s;
  __syncthreads();
  if (threadIdx.x == 0) part[pidx] = red[0] + red[1] + red[2] + red[3];
}

// ---- K3b: mu regularizer; mask recomputed from sids ----
__global__ __launch_bounds__(64) void k3_mureg(const float* __restrict__ mu_subj,
                                               const float* __restrict__ mu_pop,
                                               const int* __restrict__ sids,
                                               float* __restrict__ part) {
  int p = blockIdx.x;
  int found = 0;
  for (int b2 = 0; b2 < BB; ++b2) found |= (sids[b2] == p) ? 1 : 0;
  if (!found) {
    if (threadIdx.x == 0) part[p] = 0.f;
    return;
  }
  const float4* a4 = reinterpret_cast<const float4*>(mu_subj) + (size_t)p * (KK * DD / 4);
  const float4* b4 = reinterpret_cast<const float4*>(mu_pop);
  float s = 0.f;
#pragma unroll
  for (int q = 0; q < 5; ++q) {
    int o = q * 64 + threadIdx.x;
    float4 a = a4[o], bb = b4[o];
    float d0 = a.x - bb.x, d1 = a.y - bb.y, d2 = a.z - bb.z, d3 = a.w - bb.w;
    s += d0 * d0 + d1 * d1 + d2 * d2 + d3 * d3;
  }
  s = wave_sum(s);
  if (threadIdx.x == 0) part[p] = s;
}

// ---- K4: reduce all partials, compute n_unique, combine ----
__global__ __launch_bounds__(256) void k4_final(const int* __restrict__ sids,
                                                const float* __restrict__ ws,
                                                float* __restrict__ out) {
  int tid = threadIdx.x;
  __shared__ float nuniq;
  if (tid < 64) {  // wave 0 only: ballot over subject slots
    int found = 0;
    for (int b2 = 0; b2 < BB; ++b2) found |= (sids[b2] == tid) ? 1 : 0;
    unsigned long long bal = __ballot(found != 0);
    if (tid == 0) nuniq = (float)__popcll(bal);
  }
  __syncthreads();
  float scale = nuniq / 64.0f;

  float a = 0.f;
  for (int i = tid; i < 2048; i += 256) a += ws[WS_PART2 + i];
  float lr = 0.f;
  for (int i = tid; i < 1600; i += 256) lr += ws[WS_PART3L + i];
  float mr = 0.f;
  if (tid < 64) mr = ws[WS_PART3M + tid];

  float v = a / 32768.0f + scale * 0.05f * (lr + mr);
  v = wave_sum(v);
  __shared__ float red[4];
  if ((tid & 63) == 0) red[tid >> 6] = v;
  __syncthreads();
  if (tid == 0) out[0] = red[0] + red[1] + red[2] + red[3];
}

extern "C" void kernel_launch(void* const* d_in, const int* in_sizes, int n_in,
                              void* d_out, int out_size, void* d_ws, size_t ws_size,
                              hipStream_t stream) {
  const float* x       = (const float*)d_in[0];
  const float* mu_pop  = (const float*)d_in[1];
  const float* L_pop   = (const float*)d_in[2];
  const float* mu_subj = (const float*)d_in[3];
  const float* L_subj  = (const float*)d_in[4];
  const float* gamma   = (const float*)d_in[5];
  const int*   sids    = (const int*)d_in[6];
  float* out = (float*)d_out;
  float* ws  = (float*)d_ws;

  hipLaunchKernelGGL(kx_cast, dim3(BB * TTOT * DD / 4 / 256), dim3(256), 0, stream, x, ws);
  hipLaunchKernelGGL(k1_inv, dim3(KK, BB), dim3(128), 0, stream, L_subj, mu_subj, sids, ws);
  hipLaunchKernelGGL(k2_mfma, dim3(KK, TTOT / 256, BB), dim3(256), 0, stream,
                     gamma, ws, ws + WS_PART2);
  hipLaunchKernelGGL(k3_lreg, dim3(25, PP), dim3(256), 0, stream,
                     L_subj, L_pop, sids, ws + WS_PART3L);
  hipLaunchKernelGGL(k3_mureg, dim3(PP), dim3(64), 0, stream,
                     mu_subj, mu_pop, sids, ws + WS_PART3M);
  hipLaunchKernelGGL(k4_final, dim3(1), dim3(256), 0, stream, sids, ws, out);
}

// Round 12
// 73.594 us; speedup vs baseline: 1.2404x; 1.2404x over previous
//
#include <hip/hip_runtime.h>
#include <hip/hip_bf16.h>
#include <math.h>

#define BB 32
#define TTOT 1024
#define KK 16
#define DD 80
#define PP 64

// workspace layout (float offsets)
#define WS_DCONST 128      // 512 = B*K
#define WS_CVEC   1024     // 512*80 -> ends 41984
#define WS_PART2  41984    // 2048 (k2 per-block partials) -> 44032
#define WS_PART3L 44032    // 1600 (k3_lreg per-block partials) -> 45632
#define WS_PART3M 45632    // 64 (k3_mureg per-block partials) -> 45696
#define WS_XBF16  46080    // bf16[32*1024*80] = 1,310,720 floats -> ends 1,356,800
#define WS_MINVB  1356800  // bf16[512*80*80]  = 1,638,400 floats -> ends 2,995,200 (12.0 MB)

typedef short bf16x8 __attribute__((ext_vector_type(8)));
typedef float f32x4 __attribute__((ext_vector_type(4)));

__device__ __forceinline__ float wave_sum(float v) {
#pragma unroll
  for (int o = 32; o > 0; o >>= 1) v += __shfl_down(v, o);
  return v;
}

__device__ __forceinline__ unsigned short f2bf(float f) {
  __hip_bfloat16 h = __float2bfloat16(f);
  return *reinterpret_cast<unsigned short*>(&h);
}

// ---- KX: x fp32 -> bf16 (same layout) ----
__global__ __launch_bounds__(256) void kx_cast(const float* __restrict__ x,
                                               float* __restrict__ ws) {
  size_t idx = (size_t)blockIdx.x * 256 + threadIdx.x;  // one per 4 floats
  float4 v = reinterpret_cast<const float4*>(x)[idx];
  uint2 o;
  o.x = ((unsigned)f2bf(v.y) << 16) | f2bf(v.x);
  o.y = ((unsigned)f2bf(v.w) << 16) | f2bf(v.z);
  reinterpret_cast<uint2*>((__hip_bfloat16*)(ws + WS_XBF16))[idx] = o;
}

// ---- K1: per (b,k) triangular inverse; emit Minv as bf16, c fp32, dconst ----
// R6-R11 lesson: the cost was load latency inside 16-level triangular chains at
// 1 wave/SIMD. Redesign: Phase 1 inverts the five 16x16 DIAGONAL blocks in
// parallel (the only serial chain left: 120 register FMAs per 16-thread group).
// Phase 2 is chain-free: y[ci] = Dinv[ci]*(e - sum L[ci][cm]*y[cm]) -- dense
// FMAs on independent accumulators, L LDS-staged (R9), per-thread arrays
// 16-wide static, each thread owns one Minv column (no barriers in recursion).
__global__ __launch_bounds__(128, 1) void k1_inv(const float* __restrict__ L_subj,
                                                 const float* __restrict__ mu_subj,
                                                 const int* __restrict__ sids,
                                                 float* __restrict__ ws) {
  int k = blockIdx.x, b = blockIdx.y;
  int p = sids[b];
  const float* Lg = L_subj + ((size_t)(p * KK + k)) * DD * DD;
  const float* mug = mu_subj + (size_t)(p * KK + k) * DD;
  int bk = b * KK + k;

  __shared__ float Ls[DD * 84];        // staged L, stride 84 (16B-aligned rows)
  __shared__ float ys[DD * 81 + 64];   // Minv (fp32), stride 81; +64 OOB pad
  __shared__ float dinv[DD * 20];      // five 16x16 Dinv blocks, row stride 20
  __shared__ float rdiag[DD];
  __shared__ float lgd[DD];

  int tid = threadIdx.x;

  // stage L: 1600 float4 coalesced reads, aligned float4 LDS writes
  {
    const float4* Lg4 = reinterpret_cast<const float4*>(Lg);
    for (int idx = tid; idx < DD * DD / 4; idx += 128) {
      float4 v = Lg4[idx];
      int r = idx / (DD / 4), c0 = (idx % (DD / 4)) * 4;
      *reinterpret_cast<float4*>(&Ls[r * 84 + c0]) = v;
    }
  }
  __syncthreads();

  if (tid < DD) {
    float dv = Ls[tid * 84 + tid];
    rdiag[tid] = 1.0f / dv;
    lgd[tid] = logf(dv);
  }
  __syncthreads();

  // ---- Phase 1: invert diagonal 16x16 blocks; thread = (block ci5, col jj)
  if (tid < DD) {
    const int ci5 = tid >> 4, jj = tid & 15;
    const float* Lb = &Ls[(ci5 * 16) * 84 + ci5 * 16];  // row stride 84
    float yc[16];
#pragma unroll
    for (int ii = 0; ii < 16; ++ii) {
      float v = (ii == jj) ? 1.0f : 0.0f;
#pragma unroll
      for (int mm = 0; mm < 16; ++mm)
        if (mm < ii) v = fmaf(-Lb[ii * 84 + mm], yc[mm], v);
      yc[ii] = v * rdiag[ci5 * 16 + ii];
    }
#pragma unroll
    for (int ii = 0; ii < 16; ++ii) dinv[(ci5 * 16 + ii) * 20 + jj] = yc[ii];
  }
  __syncthreads();

  // ---- Phase 2: chain-free per-column recursion (thread j = column)
  const int j = tid;
  const bool act = j < DD;
  for (int ci = 0; ci < 5; ++ci) {
    const int r0 = ci * 16;
    float s[16];
#pragma unroll
    for (int ii = 0; ii < 16; ++ii) s[ii] = (r0 + ii == j) ? 1.0f : 0.0f;
    // cross-block contributions (prior y blocks are exact zeros above diag)
    for (int cp = 0; cp < ci; ++cp) {
      float ym[16];
#pragma unroll
      for (int m = 0; m < 16; ++m) ym[m] = ys[(cp * 16 + m) * 81 + j];
#pragma unroll
      for (int ii = 0; ii < 16; ++ii) {
        const float4* Lr = reinterpret_cast<const float4*>(&Ls[(r0 + ii) * 84 + cp * 16]);
        float4 a0 = Lr[0], a1 = Lr[1], a2 = Lr[2], a3 = Lr[3];
        float t = s[ii];
        t = fmaf(-a0.x, ym[0], t);  t = fmaf(-a0.y, ym[1], t);
        t = fmaf(-a0.z, ym[2], t);  t = fmaf(-a0.w, ym[3], t);
        t = fmaf(-a1.x, ym[4], t);  t = fmaf(-a1.y, ym[5], t);
        t = fmaf(-a1.z, ym[6], t);  t = fmaf(-a1.w, ym[7], t);
        t = fmaf(-a2.x, ym[8], t);  t = fmaf(-a2.y, ym[9], t);
        t = fmaf(-a2.z, ym[10], t); t = fmaf(-a2.w, ym[11], t);
        t = fmaf(-a3.x, ym[12], t); t = fmaf(-a3.y, ym[13], t);
        t = fmaf(-a3.z, ym[14], t); t = fmaf(-a3.w, ym[15], t);
        s[ii] = t;
      }
    }
    // y[ci] = Dinv[ci] * s : dense 16x16 matvec, uniform float4 LDS reads
    float yc[16];
#pragma unroll
    for (int ii = 0; ii < 16; ++ii) {
      const float4* dr = reinterpret_cast<const float4*>(&dinv[(r0 + ii) * 20]);
      float4 d0 = dr[0], d1 = dr[1], d2 = dr[2], d3 = dr[3];
      float t = 0.f;
      t = fmaf(d0.x, s[0], t);   t = fmaf(d0.y, s[1], t);
      t = fmaf(d0.z, s[2], t);   t = fmaf(d0.w, s[3], t);
      t = fmaf(d1.x, s[4], t);   t = fmaf(d1.y, s[5], t);
      t = fmaf(d1.z, s[6], t);   t = fmaf(d1.w, s[7], t);
      t = fmaf(d2.x, s[8], t);   t = fmaf(d2.y, s[9], t);
      t = fmaf(d2.z, s[10], t);  t = fmaf(d2.w, s[11], t);
      t = fmaf(d3.x, s[12], t);  t = fmaf(d3.y, s[13], t);
      t = fmaf(d3.z, s[14], t);  t = fmaf(d3.w, s[15], t);
      yc[ii] = t;
    }
    if (act) {
#pragma unroll
      for (int ii = 0; ii < 16; ++ii) ys[(r0 + ii) * 81 + j] = yc[ii];
    }
  }
  __syncthreads();

  // coalesced bf16 write of Minv rows (2 bf16 per uint)
  unsigned* Mg = reinterpret_cast<unsigned*>(
      (__hip_bfloat16*)(ws + WS_MINVB) + (size_t)bk * DD * DD);
  for (int idx = tid; idx < DD * (DD / 2); idx += 128) {
    int i = idx / (DD / 2), jp = idx % (DD / 2);
    unsigned u = ((unsigned)f2bf(ys[i * 81 + 2 * jp + 1]) << 16) | f2bf(ys[i * 81 + 2 * jp]);
    Mg[idx] = u;
  }

  if (tid < DD) {
    int i = tid;
    float ci = 0.f;
#pragma unroll 8
    for (int jj = 0; jj < DD; ++jj) ci = fmaf(ys[i * 81 + jj], mug[jj], ci);
    ws[WS_CVEC + bk * DD + i] = ci;
  }
  if (tid == 0) {
    float s = 0.f;
    for (int i = 0; i < DD; ++i) s += lgd[i];
    ws[WS_DCONST + bk] = (float)(0.5 * 80.0 * 1.8378770664093453) + s;  // 0.5*D*ln(2pi)+logdet
  }
}

// ---- K2: MFMA main loss. Block = (k, ttile of 256, b); 4 waves x 64 t. ----
// Writes ONE partial per block (no global atomics).
__global__ __launch_bounds__(256) void k2_mfma(const float* __restrict__ gamma,
                                               const float* __restrict__ ws,
                                               float* __restrict__ part) {
  const int k = blockIdx.x, tt = blockIdx.y, b = blockIdx.z;
  const int w = threadIdx.x >> 6, l = threadIdx.x & 63;
  const int lg = l >> 4, lr = l & 15;
  const int bk = b * KK + k;

  const __hip_bfloat16* Xb = (const __hip_bfloat16*)(ws + WS_XBF16) + (size_t)b * TTOT * DD;
  const __hip_bfloat16* Mb = (const __hip_bfloat16*)(ws + WS_MINVB) + (size_t)bk * DD * DD;
  const float* cc = ws + WS_CVEC + bk * DD;
  const float dconst = ws[WS_DCONST + bk];

  const int t0 = tt * 256 + w * 64;  // wave's t base

  f32x4 accf[5][4] = {};  // [m-tile][n-frag]
#pragma unroll
  for (int c = 0; c < 3; ++c) {
    const int j = c * 32 + lg * 8;
    const bool dead = (c == 2) && (lg >= 2);  // j >= 80: zero-pad K to 96
    bf16x8 af[5], bf[4];
#pragma unroll
    for (int mt = 0; mt < 5; ++mt)
      af[mt] = dead ? (bf16x8){} : *(const bf16x8*)(Mb + (mt * 16 + lr) * DD + j);
#pragma unroll
    for (int nf = 0; nf < 4; ++nf)
      bf[nf] = dead ? (bf16x8){} : *(const bf16x8*)(Xb + (size_t)(t0 + nf * 16 + lr) * DD + j);
#pragma unroll
    for (int mt = 0; mt < 5; ++mt)
#pragma unroll
      for (int nf = 0; nf < 4; ++nf)
        accf[mt][nf] = __builtin_amdgcn_mfma_f32_16x16x32_bf16(af[mt], bf[nf], accf[mt][nf], 0, 0, 0);
  }

  // epilogue: maha per t, gamma-weighted accumulate
  float c_r[5][4];
#pragma unroll
  for (int mt = 0; mt < 5; ++mt)
#pragma unroll
    for (int r = 0; r < 4; ++r)
      c_r[mt][r] = cc[mt * 16 + lg * 4 + r];  // row i = mt*16 + lg*4 + r

  float v = 0.f;
#pragma unroll
  for (int nf = 0; nf < 4; ++nf) {
    float s = 0.f;
#pragma unroll
    for (int mt = 0; mt < 5; ++mt)
#pragma unroll
      for (int r = 0; r < 4; ++r) {
        float z = accf[mt][nf][r] - c_r[mt][r];
        s = fmaf(z, z, s);
      }
    s += __shfl_xor(s, 16);
    s += __shfl_xor(s, 32);  // all 4 lane-groups combined: full maha for col lr
    float g = 0.f;
    int t = t0 + nf * 16 + lr;
    if (l < 16) g = gamma[((size_t)b * TTOT + t) * KK + k];
    v = fmaf(g, dconst + 0.5f * s, v);
  }
  v = wave_sum(v);

  __shared__ float red[4];
  if (l == 0) red[w] = v;
  __syncthreads();
  if (threadIdx.x == 0)
    part[(b * 4 + tt) * KK + k] = red[0] + red[1] + red[2] + red[3];
}

// ---- K3: L regularizer; mask recomputed from sids ----
__global__ __launch_bounds__(256) void k3_lreg(const float* __restrict__ L_subj,
                                               const float* __restrict__ L_pop,
                                               const int* __restrict__ sids,
                                               float* __restrict__ part) {
  int p = blockIdx.y;
  int chunk = blockIdx.x;  // 25 chunks x 1024 float4 per subject
  int pidx = p * 25 + chunk;
  int found = 0;
  for (int b2 = 0; b2 < BB; ++b2) found |= (sids[b2] == p) ? 1 : 0;
  if (!found) {
    if (threadIdx.x == 0) part[pidx] = 0.f;
    return;
  }
  const float4* a4 = reinterpret_cast<const float4*>(L_subj) + (size_t)p * (KK * DD * DD / 4);
  const float4* b4 = reinterpret_cast<const float4*>(L_pop);
  float s = 0.f;
#pragma unroll
  for (int q = 0; q < 4; ++q) {
    int o = chunk * 1024 + q * 256 + threadIdx.x;
    float4 a = a4[o], bb = b4[o];
    float d0 = a.x - bb.x, d1 = a.y - bb.y, d2 = a.z - bb.z, d3 = a.w - bb.w;
    s += d0 * d0 + d1 * d1 + d2 * d2 + d3 * d3;
  }
  s = wave_sum(s);
  __shared__ float red[4];
  if ((threadIdx.x & 63) == 0) red[threadIdx.x >> 6] = s;
  __syncthreads();
  if (threadIdx.x == 0) part[pidx] = red[0] + red[1] + red[2] + red[3];
}

// ---- K3b: mu regularizer; mask recomputed from sids ----
__global__ __launch_bounds__(64) void k3_mureg(const float* __restrict__ mu_subj,
                                               const float* __restrict__ mu_pop,
                                               const int* __restrict__ sids,
                                               float* __restrict__ part) {
  int p = blockIdx.x;
  int found = 0;
  for (int b2 = 0; b2 < BB; ++b2) found |= (sids[b2] == p) ? 1 : 0;
  if (!found) {
    if (threadIdx.x == 0) part[p] = 0.f;
    return;
  }
  const float4* a4 = reinterpret_cast<const float4*>(mu_subj) + (size_t)p * (KK * DD / 4);
  const float4* b4 = reinterpret_cast<const float4*>(mu_pop);
  float s = 0.f;
#pragma unroll
  for (int q = 0; q < 5; ++q) {
    int o = q * 64 + threadIdx.x;
    float4 a = a4[o], bb = b4[o];
    float d0 = a.x - bb.x, d1 = a.y - bb.y, d2 = a.z - bb.z, d3 = a.w - bb.w;
    s += d0 * d0 + d1 * d1 + d2 * d2 + d3 * d3;
  }
  s = wave_sum(s);
  if (threadIdx.x == 0) part[p] = s;
}

// ---- K4: reduce all partials, compute n_unique, combine ----
__global__ __launch_bounds__(256) void k4_final(const int* __restrict__ sids,
                                                const float* __restrict__ ws,
                                                float* __restrict__ out) {
  int tid = threadIdx.x;
  __shared__ float nuniq;
  if (tid < 64) {  // wave 0 only: ballot over subject slots
    int found = 0;
    for (int b2 = 0; b2 < BB; ++b2) found |= (sids[b2] == tid) ? 1 : 0;
    unsigned long long bal = __ballot(found != 0);
    if (tid == 0) nuniq = (float)__popcll(bal);
  }
  __syncthreads();
  float scale = nuniq / 64.0f;

  float a = 0.f;
  for (int i = tid; i < 2048; i += 256) a += ws[WS_PART2 + i];
  float lr = 0.f;
  for (int i = tid; i < 1600; i += 256) lr += ws[WS_PART3L + i];
  float mr = 0.f;
  if (tid < 64) mr = ws[WS_PART3M + tid];

  float v = a / 32768.0f + scale * 0.05f * (lr + mr);
  v = wave_sum(v);
  __shared__ float red[4];
  if ((tid & 63) == 0) red[tid >> 6] = v;
  __syncthreads();
  if (tid == 0) out[0] = red[0] + red[1] + red[2] + red[3];
}

extern "C" void kernel_launch(void* const* d_in, const int* in_sizes, int n_in,
                              void* d_out, int out_size, void* d_ws, size_t ws_size,
                              hipStream_t stream) {
  const float* x       = (const float*)d_in[0];
  const float* mu_pop  = (const float*)d_in[1];
  const float* L_pop   = (const float*)d_in[2];
  const float* mu_subj = (const float*)d_in[3];
  const float* L_subj  = (const float*)d_in[4];
  const float* gamma   = (const float*)d_in[5];
  const int*   sids    = (const int*)d_in[6];
  float* out = (float*)d_out;
  float* ws  = (float*)d_ws;

  hipLaunchKernelGGL(kx_cast, dim3(BB * TTOT * DD / 4 / 256), dim3(256), 0, stream, x, ws);
  hipLaunchKernelGGL(k1_inv, dim3(KK, BB), dim3(128), 0, stream, L_subj, mu_subj, sids, ws);
  hipLaunchKernelGGL(k2_mfma, dim3(KK, TTOT / 256, BB), dim3(256), 0, stream,
                     gamma, ws, ws + WS_PART2);
  hipLaunchKernelGGL(k3_lreg, dim3(25, PP), dim3(256), 0, stream,
                     L_subj, L_pop, sids, ws + WS_PART3L);
  hipLaunchKernelGGL(k3_mureg, dim3(PP), dim3(64), 0, stream,
                     mu_subj, mu_pop, sids, ws + WS_PART3M);
  hipLaunchKernelGGL(k4_final, dim3(1), dim3(256), 0, stream, sids, ws, out);
}

// Round 13
// 59.899 us; speedup vs baseline: 1.5240x; 1.2286x over previous
//
#include <hip/hip_runtime.h>
#include <hip/hip_bf16.h>
#include <math.h>

#define BB 32
#define TTOT 1024
#define KK 16
#define DD 80
#define PP 64

// workspace layout (float offsets)
#define WS_DCONST 128      // 512 = B*K
#define WS_CVEC   1024     // 512*80 -> ends 41984
#define WS_PART2  41984    // 2048 (k2 per-block partials) -> 44032
#define WS_PART3L 44032    // 1600 (k3_lreg per-block partials) -> 45632
#define WS_PART3M 45632    // 64 (k3_mureg per-block partials) -> 45696
#define WS_XBF16  46080    // bf16[32*1024*80] = 1,310,720 floats -> ends 1,356,800
#define WS_MINVB  1356800  // bf16[512*80*80]  = 1,638,400 floats -> ends 2,995,200 (12.0 MB)

typedef short bf16x8 __attribute__((ext_vector_type(8)));
typedef float f32x4 __attribute__((ext_vector_type(4)));

__device__ __forceinline__ float wave_sum(float v) {
#pragma unroll
  for (int o = 32; o > 0; o >>= 1) v += __shfl_down(v, o);
  return v;
}

__device__ __forceinline__ unsigned short f2bf(float f) {
  __hip_bfloat16 h = __float2bfloat16(f);
  return *reinterpret_cast<unsigned short*>(&h);
}

__device__ __forceinline__ bf16x8 pack8(float4 a, float4 b) {
  bf16x8 r;
  r[0] = (short)f2bf(a.x); r[1] = (short)f2bf(a.y);
  r[2] = (short)f2bf(a.z); r[3] = (short)f2bf(a.w);
  r[4] = (short)f2bf(b.x); r[5] = (short)f2bf(b.y);
  r[6] = (short)f2bf(b.z); r[7] = (short)f2bf(b.w);
  return r;
}

// ---- KX: x fp32 -> bf16 (same layout) ----
__global__ __launch_bounds__(256) void kx_cast(const float* __restrict__ x,
                                               float* __restrict__ ws) {
  size_t idx = (size_t)blockIdx.x * 256 + threadIdx.x;  // one per 4 floats
  float4 v = reinterpret_cast<const float4*>(x)[idx];
  uint2 o;
  o.x = ((unsigned)f2bf(v.y) << 16) | f2bf(v.x);
  o.y = ((unsigned)f2bf(v.w) << 16) | f2bf(v.z);
  reinterpret_cast<uint2*>((__hip_bfloat16*)(ws + WS_XBF16))[idx] = o;
}

// ---- K1: per (b,k) triangular inverse via MFMA block recursion ----
// R12 post-mortem: Phase-2's uniform LDS broadcasts of L/Dinv ~= 10K cy/wave on
// the shared LDS pipe = the remaining ~25 us. Fix: the recursion
// Y[ci] = Dinv[ci]*(E - sum L[ci][cp]*Y[cp]) is 16x16 GEMMs -> run it on the
// MFMA pipe with k2's PROVEN 16x16x32 bf16 layouts. A-frags are per-lane 32B
// loads (L: global/L2, Dinv: LDS); Y round-trips C-frag->LDS->B-frag (C layout
// col=l&15,row=(l>>4)*4+r matches B's col=l&15,k-rows). Odd-K chunks zero BOTH
// A and B halves (no 0*garbage NaN). Wave 0 owns col-tiles 0-2, wave 1 owns
// 3-4: columns are solve-independent -> no cross-wave sync in the recursion.
__global__ __launch_bounds__(128, 1) void k1_inv(const float* __restrict__ L_subj,
                                                 const float* __restrict__ mu_subj,
                                                 const int* __restrict__ sids,
                                                 float* __restrict__ ws) {
  int k = blockIdx.x, b = blockIdx.y;
  int p = sids[b];
  const float* Lg = L_subj + ((size_t)(p * KK + k)) * DD * DD;
  const float* mug = mu_subj + (size_t)(p * KK + k) * DD;
  int bk = b * KK + k;

  __shared__ float ys[DD * 81 + 64];   // Minv fp32 (MFMA C accum), stride 81
  __shared__ float dinv[DD * 20];      // five 16x16 Dinv blocks, row stride 20
  __shared__ float lgd[DD];
  __shared__ float rt[2][16 * 17];     // per-wave R bounce tile

  const int tid = threadIdx.x;
  const int w = tid >> 6, l = tid & 63;
  const int lr = l & 15, lg = l >> 4;

  // ---- Phase 1: invert diagonal 16x16 blocks (fp32, registers, static idx)
  if (tid < DD) {
    const int ci5 = tid >> 4, jj = tid & 15;
    const float* Lb = Lg + (ci5 * 16) * DD + ci5 * 16;
    float yc[16];
#pragma unroll
    for (int ii = 0; ii < 16; ++ii) {
      float v = (ii == jj) ? 1.0f : 0.0f;
#pragma unroll
      for (int mm = 0; mm < 16; ++mm)
        if (mm < ii) v = fmaf(-Lb[ii * DD + mm], yc[mm], v);
      yc[ii] = v / Lb[ii * DD + ii];
    }
#pragma unroll
    for (int ii = 0; ii < 16; ++ii) dinv[(ci5 * 16 + ii) * 20 + jj] = yc[ii];
    lgd[tid] = logf(Lg[tid * DD + tid]);
  }
  __syncthreads();

  // ---- Phase 2: MFMA block recursion; wave w owns col-tiles [nt0,nt1)
  const int nt0 = (w == 0) ? 0 : 3;
  const int nt1 = (w == 0) ? 3 : 5;
  float* rtw = rt[w];

  for (int ci = 0; ci < 5; ++ci) {
    const int r0 = ci * 16;
    const int ktot = ci * 16;          // cross-term K extent
    const int nch = (ci + 1) >> 1;     // K=32 chunks (last may be half)

    // A-frags for this level: L row-block pieces + Dinv (per-lane 32B loads)
    bf16x8 aL0 = {}, aL1 = {};
    if (nch > 0 && (0 + lg * 8) < ktot) {
      const float* src = &Lg[(r0 + lr) * DD + lg * 8];
      aL0 = pack8(*reinterpret_cast<const float4*>(src),
                  *reinterpret_cast<const float4*>(src + 4));
    }
    if (nch > 1 && (32 + lg * 8) < ktot) {
      const float* src = &Lg[(r0 + lr) * DD + 32 + lg * 8];
      aL1 = pack8(*reinterpret_cast<const float4*>(src),
                  *reinterpret_cast<const float4*>(src + 4));
    }
    bf16x8 aD = {};
    if (lg < 2) {
      const float* src = &dinv[(r0 + lr) * 20 + lg * 8];
      aD = pack8(*reinterpret_cast<const float4*>(src),
                 *reinterpret_cast<const float4*>(src + 4));
    }

    for (int nt = nt0; nt < nt1; ++nt) {
      const int col = nt * 16 + lr;
      f32x4 S = {};
      if (nch > 0) {
        bf16x8 b0 = {};
        if ((0 + lg * 8) < ktot) {
          const int kb = lg * 8;
#pragma unroll
          for (int jj = 0; jj < 8; ++jj)
            b0[jj] = (short)f2bf(ys[(kb + jj) * 81 + col]);
        }
        S = __builtin_amdgcn_mfma_f32_16x16x32_bf16(aL0, b0, S, 0, 0, 0);
      }
      if (nch > 1) {
        bf16x8 b1 = {};
        if ((32 + lg * 8) < ktot) {
          const int kb = 32 + lg * 8;
#pragma unroll
          for (int jj = 0; jj < 8; ++jj)
            b1[jj] = (short)f2bf(ys[(kb + jj) * 81 + col]);
        }
        S = __builtin_amdgcn_mfma_f32_16x16x32_bf16(aL1, b1, S, 0, 0, 0);
      }
      // R = E - S in C-layout; bounce through LDS to B-layout
#pragma unroll
      for (int r = 0; r < 4; ++r) {
        float e = (r0 + lg * 4 + r == col) ? 1.0f : 0.0f;
        rtw[(lg * 4 + r) * 17 + lr] = e - S[r];
      }
      bf16x8 bR = {};
      if (lg < 2) {
#pragma unroll
        for (int jj = 0; jj < 8; ++jj)
          bR[jj] = (short)f2bf(rtw[(lg * 8 + jj) * 17 + lr]);
      }
      f32x4 Y = {};
      Y = __builtin_amdgcn_mfma_f32_16x16x32_bf16(aD, bR, Y, 0, 0, 0);
#pragma unroll
      for (int r = 0; r < 4; ++r) ys[(r0 + lg * 4 + r) * 81 + col] = Y[r];
    }
  }
  __syncthreads();

  // coalesced bf16 write of Minv rows (2 bf16 per uint)
  unsigned* Mg = reinterpret_cast<unsigned*>(
      (__hip_bfloat16*)(ws + WS_MINVB) + (size_t)bk * DD * DD);
  for (int idx = tid; idx < DD * (DD / 2); idx += 128) {
    int i = idx / (DD / 2), jp = idx % (DD / 2);
    unsigned u = ((unsigned)f2bf(ys[i * 81 + 2 * jp + 1]) << 16) | f2bf(ys[i * 81 + 2 * jp]);
    Mg[idx] = u;
  }

  if (tid < DD) {
    int i = tid;
    float ci = 0.f;
#pragma unroll 8
    for (int jj = 0; jj < DD; ++jj) ci = fmaf(ys[i * 81 + jj], mug[jj], ci);
    ws[WS_CVEC + bk * DD + i] = ci;
  }
  if (tid == 0) {
    float s = 0.f;
    for (int i = 0; i < DD; ++i) s += lgd[i];
    ws[WS_DCONST + bk] = (float)(0.5 * 80.0 * 1.8378770664093453) + s;  // 0.5*D*ln(2pi)+logdet
  }
}

// ---- K2: MFMA main loss. Block = (k, ttile of 256, b); 4 waves x 64 t. ----
// Writes ONE partial per block (no global atomics).
__global__ __launch_bounds__(256) void k2_mfma(const float* __restrict__ gamma,
                                               const float* __restrict__ ws,
                                               float* __restrict__ part) {
  const int k = blockIdx.x, tt = blockIdx.y, b = blockIdx.z;
  const int w = threadIdx.x >> 6, l = threadIdx.x & 63;
  const int lg = l >> 4, lr = l & 15;
  const int bk = b * KK + k;

  const __hip_bfloat16* Xb = (const __hip_bfloat16*)(ws + WS_XBF16) + (size_t)b * TTOT * DD;
  const __hip_bfloat16* Mb = (const __hip_bfloat16*)(ws + WS_MINVB) + (size_t)bk * DD * DD;
  const float* cc = ws + WS_CVEC + bk * DD;
  const float dconst = ws[WS_DCONST + bk];

  const int t0 = tt * 256 + w * 64;  // wave's t base

  f32x4 accf[5][4] = {};  // [m-tile][n-frag]
#pragma unroll
  for (int c = 0; c < 3; ++c) {
    const int j = c * 32 + lg * 8;
    const bool dead = (c == 2) && (lg >= 2);  // j >= 80: zero-pad K to 96
    bf16x8 af[5], bf[4];
#pragma unroll
    for (int mt = 0; mt < 5; ++mt)
      af[mt] = dead ? (bf16x8){} : *(const bf16x8*)(Mb + (mt * 16 + lr) * DD + j);
#pragma unroll
    for (int nf = 0; nf < 4; ++nf)
      bf[nf] = dead ? (bf16x8){} : *(const bf16x8*)(Xb + (size_t)(t0 + nf * 16 + lr) * DD + j);
#pragma unroll
    for (int mt = 0; mt < 5; ++mt)
#pragma unroll
      for (int nf = 0; nf < 4; ++nf)
        accf[mt][nf] = __builtin_amdgcn_mfma_f32_16x16x32_bf16(af[mt], bf[nf], accf[mt][nf], 0, 0, 0);
  }

  // epilogue: maha per t, gamma-weighted accumulate
  float c_r[5][4];
#pragma unroll
  for (int mt = 0; mt < 5; ++mt)
#pragma unroll
    for (int r = 0; r < 4; ++r)
      c_r[mt][r] = cc[mt * 16 + lg * 4 + r];  // row i = mt*16 + lg*4 + r

  float v = 0.f;
#pragma unroll
  for (int nf = 0; nf < 4; ++nf) {
    float s = 0.f;
#pragma unroll
    for (int mt = 0; mt < 5; ++mt)
#pragma unroll
      for (int r = 0; r < 4; ++r) {
        float z = accf[mt][nf][r] - c_r[mt][r];
        s = fmaf(z, z, s);
      }
    s += __shfl_xor(s, 16);
    s += __shfl_xor(s, 32);  // all 4 lane-groups combined: full maha for col lr
    float g = 0.f;
    int t = t0 + nf * 16 + lr;
    if (l < 16) g = gamma[((size_t)b * TTOT + t) * KK + k];
    v = fmaf(g, dconst + 0.5f * s, v);
  }
  v = wave_sum(v);

  __shared__ float red[4];
  if (l == 0) red[w] = v;
  __syncthreads();
  if (threadIdx.x == 0)
    part[(b * 4 + tt) * KK + k] = red[0] + red[1] + red[2] + red[3];
}

// ---- K3: L regularizer; mask recomputed from sids ----
__global__ __launch_bounds__(256) void k3_lreg(const float* __restrict__ L_subj,
                                               const float* __restrict__ L_pop,
                                               const int* __restrict__ sids,
                                               float* __restrict__ part) {
  int p = blockIdx.y;
  int chunk = blockIdx.x;  // 25 chunks x 1024 float4 per subject
  int pidx = p * 25 + chunk;
  int found = 0;
  for (int b2 = 0; b2 < BB; ++b2) found |= (sids[b2] == p) ? 1 : 0;
  if (!found) {
    if (threadIdx.x == 0) part[pidx] = 0.f;
    return;
  }
  const float4* a4 = reinterpret_cast<const float4*>(L_subj) + (size_t)p * (KK * DD * DD / 4);
  const float4* b4 = reinterpret_cast<const float4*>(L_pop);
  float s = 0.f;
#pragma unroll
  for (int q = 0; q < 4; ++q) {
    int o = chunk * 1024 + q * 256 + threadIdx.x;
    float4 a = a4[o], bb = b4[o];
    float d0 = a.x - bb.x, d1 = a.y - bb.y, d2 = a.z - bb.z, d3 = a.w - bb.w;
    s += d0 * d0 + d1 * d1 + d2 * d2 + d3 * d3;
  }
  s = wave_sum(s);
  __shared__ float red[4];
  if ((threadIdx.x & 63) == 0) red[threadIdx.x >> 6] = s;
  __syncthreads();
  if (threadIdx.x == 0) part[pidx] = red[0] + red[1] + red[2] + red[3];
}

// ---- K3b: mu regularizer; mask recomputed from sids ----
__global__ __launch_bounds__(64) void k3_mureg(const float* __restrict__ mu_subj,
                                               const float* __restrict__ mu_pop,
                                               const int* __restrict__ sids,
                                               float* __restrict__ part) {
  int p = blockIdx.x;
  int found = 0;
  for (int b2 = 0; b2 < BB; ++b2) found |= (sids[b2] == p) ? 1 : 0;
  if (!found) {
    if (threadIdx.x == 0) part[p] = 0.f;
    return;
  }
  const float4* a4 = reinterpret_cast<const float4*>(mu_subj) + (size_t)p * (KK * DD / 4);
  const float4* b4 = reinterpret_cast<const float4*>(mu_pop);
  float s = 0.f;
#pragma unroll
  for (int q = 0; q < 5; ++q) {
    int o = q * 64 + threadIdx.x;
    float4 a = a4[o], bb = b4[o];
    float d0 = a.x - bb.x, d1 = a.y - bb.y, d2 = a.z - bb.z, d3 = a.w - bb.w;
    s += d0 * d0 + d1 * d1 + d2 * d2 + d3 * d3;
  }
  s = wave_sum(s);
  if (threadIdx.x == 0) part[p] = s;
}

// ---- K4: reduce all partials, compute n_unique, combine ----
__global__ __launch_bounds__(256) void k4_final(const int* __restrict__ sids,
                                                const float* __restrict__ ws,
                                                float* __restrict__ out) {
  int tid = threadIdx.x;
  __shared__ float nuniq;
  if (tid < 64) {  // wave 0 only: ballot over subject slots
    int found = 0;
    for (int b2 = 0; b2 < BB; ++b2) found |= (sids[b2] == tid) ? 1 : 0;
    unsigned long long bal = __ballot(found != 0);
    if (tid == 0) nuniq = (float)__popcll(bal);
  }
  __syncthreads();
  float scale = nuniq / 64.0f;

  float a = 0.f;
  for (int i = tid; i < 2048; i += 256) a += ws[WS_PART2 + i];
  float lr = 0.f;
  for (int i = tid; i < 1600; i += 256) lr += ws[WS_PART3L + i];
  float mr = 0.f;
  if (tid < 64) mr = ws[WS_PART3M + tid];

  float v = a / 32768.0f + scale * 0.05f * (lr + mr);
  v = wave_sum(v);
  __shared__ float red[4];
  if ((tid & 63) == 0) red[tid >> 6] = v;
  __syncthreads();
  if (tid == 0) out[0] = red[0] + red[1] + red[2] + red[3];
}

extern "C" void kernel_launch(void* const* d_in, const int* in_sizes, int n_in,
                              void* d_out, int out_size, void* d_ws, size_t ws_size,
                              hipStream_t stream) {
  const float* x       = (const float*)d_in[0];
  const float* mu_pop  = (const float*)d_in[1];
  const float* L_pop   = (const float*)d_in[2];
  const float* mu_subj = (const float*)d_in[3];
  const float* L_subj  = (const float*)d_in[4];
  const float* gamma   = (const float*)d_in[5];
  const int*   sids    = (const int*)d_in[6];
  float* out = (float*)d_out;
  float* ws  = (float*)d_ws;

  hipLaunchKernelGGL(kx_cast, dim3(BB * TTOT * DD / 4 / 256), dim3(256), 0, stream, x, ws);
  hipLaunchKernelGGL(k1_inv, dim3(KK, BB), dim3(128), 0, stream, L_subj, mu_subj, sids, ws);
  hipLaunchKernelGGL(k2_mfma, dim3(KK, TTOT / 256, BB), dim3(256), 0, stream,
                     gamma, ws, ws + WS_PART2);
  hipLaunchKernelGGL(k3_lreg, dim3(25, PP), dim3(256), 0, stream,
                     L_subj, L_pop, sids, ws + WS_PART3L);
  hipLaunchKernelGGL(k3_mureg, dim3(PP), dim3(64), 0, stream,
                     mu_subj, mu_pop, sids, ws + WS_PART3M);
  hipLaunchKernelGGL(k4_final, dim3(1), dim3(256), 0, stream, sids, ws, out);
}

// Round 15
// 59.532 us; speedup vs baseline: 1.5334x; 1.0062x over previous
//
#include <hip/hip_runtime.h>
#include <hip/hip_bf16.h>
#include <math.h>

#define BB 32
#define TTOT 1024
#define KK 16
#define DD 80
#define PP 64

// workspace layout (float offsets)
#define WS_DCONST 128      // 512
#define WS_CVEC   1024     // 512*80 -> 41984
#define WS_PART2  41984    // 2048 -> 44032
#define WS_PART3L 44032    // 1600 -> 45632
#define WS_PART3M 45632    // 64 -> 45696
#define WS_GAMT   46080    // gamma^T fp32 [32][16][1024] = 524288 -> 570368
#define WS_XBF16  570368   // X frag-major bf16: 2048 grp * 1536 = 1,572,864 fl -> 2,143,232
#define WS_MINVB  2143232  // Minv frag-major bf16: 512 * 7680 = 1,966,080 fl -> 4,109,312 (16.4 MB)

typedef short bf16x8 __attribute__((ext_vector_type(8)));
typedef float f32x4 __attribute__((ext_vector_type(4)));

__device__ __forceinline__ float wave_sum(float v) {
#pragma unroll
  for (int o = 32; o > 0; o >>= 1) v += __shfl_down(v, o);
  return v;
}

__device__ __forceinline__ unsigned short f2bf(float f) {
  __hip_bfloat16 h = __float2bfloat16(f);
  return *reinterpret_cast<unsigned short*>(&h);
}

__device__ __forceinline__ bf16x8 pack8(float4 a, float4 b) {
  bf16x8 r;
  r[0] = (short)f2bf(a.x); r[1] = (short)f2bf(a.y);
  r[2] = (short)f2bf(a.z); r[3] = (short)f2bf(a.w);
  r[4] = (short)f2bf(b.x); r[5] = (short)f2bf(b.y);
  r[6] = (short)f2bf(b.z); r[7] = (short)f2bf(b.w);
  return r;
}

// ---- KX: x fp32 -> bf16 in B-FRAGMENT-MAJOR layout ----
// R13 post-mortem: k2's bf loads were 16B/lane at 160B row stride = 64-line
// scatter per load. Emit X so that slot (c*64 + l) of each 16-t group holds
// lane l's 8 bf16 -> k2's bf load becomes a coalesced 1KB burst.
__global__ __launch_bounds__(128) void kx_cast(const float* __restrict__ x,
                                               float* __restrict__ ws) {
  const int g = blockIdx.x;            // group = b*64 + tg (16 t-rows)
  const int tid = threadIdx.x;
  __shared__ float Lx[16][84];
  const float* src = x + (size_t)g * 1280;
  for (int idx = tid; idx < 320; idx += 128) {
    float4 v = reinterpret_cast<const float4*>(src)[idx];
    int row = idx / 20, c4 = (idx % 20) * 4;
    *reinterpret_cast<float4*>(&Lx[row][c4]) = v;
  }
  __syncthreads();
  __hip_bfloat16* Xf = (__hip_bfloat16*)(ws + WS_XBF16) + (size_t)g * 1536;
  for (int s = tid; s < 192; s += 128) {
    int c = s >> 6, l = s & 63, lg = (l >> 4), lr = l & 15;
    int col0 = c * 32 + lg * 8;
    bf16x8 v = {};
    if (col0 < DD) {
#pragma unroll
      for (int jj = 0; jj < 8; ++jj) v[jj] = (short)f2bf(Lx[lr][col0 + jj]);
    }
    *reinterpret_cast<bf16x8*>(Xf + s * 8) = v;
  }
}

// ---- KG: gamma [b][t][k] -> [b][k][t] (fp32) so k2 reads 64B lines ----
__global__ __launch_bounds__(256) void kg_t(const float* __restrict__ gamma,
                                            float* __restrict__ ws) {
  const int tc = blockIdx.x, b = blockIdx.y;
  const int tid = threadIdx.x;
  __shared__ float tile[256][17];
  const float* src = gamma + ((size_t)b * TTOT + tc * 256) * KK;
#pragma unroll
  for (int q = 0; q < 16; ++q) {
    int idx = q * 256 + tid;
    tile[idx >> 4][idx & 15] = src[idx];
  }
  __syncthreads();
  float* dst = ws + WS_GAMT + (size_t)b * KK * TTOT;
#pragma unroll
  for (int q = 0; q < 16; ++q) {
    int idx = q * 256 + tid;
    int kk = idx >> 8, tl = idx & 255;
    dst[kk * TTOT + tc * 256 + tl] = tile[tl][kk];
  }
}

// ---- K1: triangular inverse via MFMA block recursion; frag-major output ----
__global__ __launch_bounds__(128, 1) void k1_inv(const float* __restrict__ L_subj,
                                                 const float* __restrict__ mu_subj,
                                                 const int* __restrict__ sids,
                                                 float* __restrict__ ws) {
  int k = blockIdx.x, b = blockIdx.y;
  int p = sids[b];
  const float* Lg = L_subj + ((size_t)(p * KK + k)) * DD * DD;
  const float* mug = mu_subj + (size_t)(p * KK + k) * DD;
  int bk = b * KK + k;

  __shared__ float ys[DD * 81 + 64];   // Minv fp32, stride 81
  __shared__ float dinv[DD * 20];      // five 16x16 Dinv blocks, row stride 20
  __shared__ float Ls5[5][16][17];     // staged diagonal blocks
  __shared__ float lgd[DD];
  __shared__ float rt[2][16 * 17];     // per-wave R bounce tile

  const int tid = threadIdx.x;
  const int w = tid >> 6, l = tid & 63;
  const int lr = l & 15, lg = l >> 4;

  // stage diagonal 16x16 blocks (5KB, coalesced 64B quarter-wave bursts)
  for (int idx = tid; idx < 5 * 256; idx += 128) {
    int blk = idx >> 8, ii = (idx >> 4) & 15, mm = idx & 15;
    Ls5[blk][ii][mm] = Lg[(blk * 16 + ii) * DD + blk * 16 + mm];
  }
  __syncthreads();

  // ---- Phase 1: invert diagonal blocks from LDS (chain hits LDS not HBM)
  if (tid < DD) {
    const int ci5 = tid >> 4, jj = tid & 15;
    float rd[16];
#pragma unroll
    for (int ii = 0; ii < 16; ++ii) rd[ii] = 1.0f / Ls5[ci5][ii][ii];
    float yc[16];
#pragma unroll
    for (int ii = 0; ii < 16; ++ii) {
      float v = (ii == jj) ? 1.0f : 0.0f;
#pragma unroll
      for (int mm = 0; mm < 16; ++mm)
        if (mm < ii) v = fmaf(-Ls5[ci5][ii][mm], yc[mm], v);
      yc[ii] = v * rd[ii];
    }
#pragma unroll
    for (int ii = 0; ii < 16; ++ii) dinv[(ci5 * 16 + ii) * 20 + jj] = yc[ii];
    lgd[tid] = logf(Ls5[ci5][jj][jj]);
  }
  __syncthreads();

  // ---- Phase 2: MFMA block recursion; wave w owns col-tiles [nt0,nt1)
  const int nt0 = (w == 0) ? 0 : 3;
  const int nt1 = (w == 0) ? 3 : 5;
  float* rtw = rt[w];

  for (int ci = 0; ci < 5; ++ci) {
    const int r0 = ci * 16;
    const int ktot = ci * 16;
    const int nch = (ci + 1) >> 1;

    bf16x8 aL0 = {}, aL1 = {};
    if (nch > 0 && (0 + lg * 8) < ktot) {
      const float* src = &Lg[(r0 + lr) * DD + lg * 8];
      aL0 = pack8(*reinterpret_cast<const float4*>(src),
                  *reinterpret_cast<const float4*>(src + 4));
    }
    if (nch > 1 && (32 + lg * 8) < ktot) {
      const float* src = &Lg[(r0 + lr) * DD + 32 + lg * 8];
      aL1 = pack8(*reinterpret_cast<const float4*>(src),
                  *reinterpret_cast<const float4*>(src + 4));
    }
    bf16x8 aD = {};
    if (lg < 2) {
      const float* src = &dinv[(r0 + lr) * 20 + lg * 8];
      aD = pack8(*reinterpret_cast<const float4*>(src),
                 *reinterpret_cast<const float4*>(src + 4));
    }

    for (int nt = nt0; nt < nt1; ++nt) {
      const int col = nt * 16 + lr;
      f32x4 S = {};
      if (nch > 0) {
        bf16x8 b0 = {};
        if ((0 + lg * 8) < ktot) {
          const int kb = lg * 8;
#pragma unroll
          for (int jj = 0; jj < 8; ++jj)
            b0[jj] = (short)f2bf(ys[(kb + jj) * 81 + col]);
        }
        S = __builtin_amdgcn_mfma_f32_16x16x32_bf16(aL0, b0, S, 0, 0, 0);
      }
      if (nch > 1) {
        bf16x8 b1 = {};
        if ((32 + lg * 8) < ktot) {
          const int kb = 32 + lg * 8;
#pragma unroll
          for (int jj = 0; jj < 8; ++jj)
            b1[jj] = (short)f2bf(ys[(kb + jj) * 81 + col]);
        }
        S = __builtin_amdgcn_mfma_f32_16x16x32_bf16(aL1, b1, S, 0, 0, 0);
      }
#pragma unroll
      for (int r = 0; r < 4; ++r) {
        float e = (r0 + lg * 4 + r == col) ? 1.0f : 0.0f;
        rtw[(lg * 4 + r) * 17 + lr] = e - S[r];
      }
      bf16x8 bR = {};
      if (lg < 2) {
#pragma unroll
        for (int jj = 0; jj < 8; ++jj)
          bR[jj] = (short)f2bf(rtw[(lg * 8 + jj) * 17 + lr]);
      }
      f32x4 Y = {};
      Y = __builtin_amdgcn_mfma_f32_16x16x32_bf16(aD, bR, Y, 0, 0, 0);
#pragma unroll
      for (int r = 0; r < 4; ++r) ys[(r0 + lg * 4 + r) * 81 + col] = Y[r];
    }
  }
  __syncthreads();

  // Minv write in A-FRAGMENT-MAJOR layout: slot s = (mt*3+c)*64 + l holds
  // Minv[mt*16+lr][c*32+lg*8 .. +7] (zeros in K-pad) -> k2 af = 1KB burst.
  __hip_bfloat16* Mf = (__hip_bfloat16*)(ws + WS_MINVB) + (size_t)bk * 7680;
  for (int s = tid; s < 960; s += 128) {
    int mtc = s >> 6, l2 = s & 63;
    int row = (mtc / 3) * 16 + (l2 & 15);
    int col0 = (mtc % 3) * 32 + (l2 >> 4) * 8;
    bf16x8 v = {};
    if (col0 < DD) {
#pragma unroll
      for (int jj = 0; jj < 8; ++jj) v[jj] = (short)f2bf(ys[row * 81 + col0 + jj]);
    }
    *reinterpret_cast<bf16x8*>(Mf + s * 8) = v;
  }

  if (tid < DD) {
    int i = tid;
    float ci = 0.f;
#pragma unroll 8
    for (int jj = 0; jj < DD; ++jj) ci = fmaf(ys[i * 81 + jj], mug[jj], ci);
    ws[WS_CVEC + bk * DD + i] = ci;
  }
  if (tid == 0) {
    float s = 0.f;
    for (int i = 0; i < DD; ++i) s += lgd[i];
    ws[WS_DCONST + bk] = (float)(0.5 * 80.0 * 1.8378770664093453) + s;
  }
}

// ---- K2: MFMA main loss; all loads frag-major coalesced 1KB bursts ----
__global__ __launch_bounds__(256) void k2_mfma(const float* __restrict__ ws_ro,
                                               float* __restrict__ part) {
  const int k = blockIdx.x, tt = blockIdx.y, b = blockIdx.z;
  const int w = threadIdx.x >> 6, l = threadIdx.x & 63;
  const int lg = l >> 4, lr = l & 15;
  const int bk = b * KK + k;

  const __hip_bfloat16* Mf = (const __hip_bfloat16*)(ws_ro + WS_MINVB) + (size_t)bk * 7680;
  const __hip_bfloat16* Xf = (const __hip_bfloat16*)(ws_ro + WS_XBF16);
  const float* gamt = ws_ro + WS_GAMT + ((size_t)b * KK + k) * TTOT;
  const float* cc = ws_ro + WS_CVEC + bk * DD;
  const float dconst = ws_ro[WS_DCONST + bk];

  const int t0 = tt * 256 + w * 64;
  const int tg0 = tt * 16 + w * 4;     // first 16-t group of this wave

  f32x4 accf[5][4] = {};
#pragma unroll
  for (int c = 0; c < 3; ++c) {
    bf16x8 af[5], bf[4];
#pragma unroll
    for (int mt = 0; mt < 5; ++mt)
      af[mt] = *(const bf16x8*)(Mf + ((mt * 3 + c) * 64 + l) * 8);
#pragma unroll
    for (int nf = 0; nf < 4; ++nf)
      bf[nf] = *(const bf16x8*)(Xf + ((size_t)(b * 64 + tg0 + nf) * 192 + c * 64 + l) * 8);
#pragma unroll
    for (int mt = 0; mt < 5; ++mt)
#pragma unroll
      for (int nf = 0; nf < 4; ++nf)
        accf[mt][nf] = __builtin_amdgcn_mfma_f32_16x16x32_bf16(af[mt], bf[nf], accf[mt][nf], 0, 0, 0);
  }

  float c_r[5][4];
#pragma unroll
  for (int mt = 0; mt < 5; ++mt)
#pragma unroll
    for (int r = 0; r < 4; ++r)
      c_r[mt][r] = cc[mt * 16 + lg * 4 + r];

  float v = 0.f;
#pragma unroll
  for (int nf = 0; nf < 4; ++nf) {
    float s = 0.f;
#pragma unroll
    for (int mt = 0; mt < 5; ++mt)
#pragma unroll
      for (int r = 0; r < 4; ++r) {
        float z = accf[mt][nf][r] - c_r[mt][r];
        s = fmaf(z, z, s);
      }
    s += __shfl_xor(s, 16);
    s += __shfl_xor(s, 32);
    float g = 0.f;
    int t = t0 + nf * 16 + lr;
    if (l < 16) g = gamt[t];           // 16 consecutive floats = 1 cache line
    v = fmaf(g, dconst + 0.5f * s, v);
  }
  v = wave_sum(v);

  __shared__ float red[4];
  if (l == 0) red[w] = v;
  __syncthreads();
  if (threadIdx.x == 0)
    part[(b * 4 + tt) * KK + k] = red[0] + red[1] + red[2] + red[3];
}

// ---- K3: L regularizer (chunks 0-24) + mu regularizer (chunk 25) ----
__global__ __launch_bounds__(256) void k3_reg(const float* __restrict__ L_subj,
                                              const float* __restrict__ L_pop,
                                              const float* __restrict__ mu_subj,
                                              const float* __restrict__ mu_pop,
                                              const int* __restrict__ sids,
                                              float* __restrict__ ws) {
  int p = blockIdx.y;
  int chunk = blockIdx.x;  // 0-24: L chunks; 25: mu
  int found = 0;
  for (int b2 = 0; b2 < BB; ++b2) found |= (sids[b2] == p) ? 1 : 0;
  float* outp = (chunk < 25) ? &ws[WS_PART3L + p * 25 + chunk] : &ws[WS_PART3M + p];
  if (!found) {
    if (threadIdx.x == 0) *outp = 0.f;
    return;
  }
  float s = 0.f;
  if (chunk < 25) {
    const float4* a4 = reinterpret_cast<const float4*>(L_subj) + (size_t)p * (KK * DD * DD / 4);
    const float4* b4 = reinterpret_cast<const float4*>(L_pop);
#pragma unroll
    for (int q = 0; q < 4; ++q) {
      int o = chunk * 1024 + q * 256 + threadIdx.x;
      float4 a = a4[o], bb = b4[o];
      float d0 = a.x - bb.x, d1 = a.y - bb.y, d2 = a.z - bb.z, d3 = a.w - bb.w;
      s += d0 * d0 + d1 * d1 + d2 * d2 + d3 * d3;
    }
  } else {
    const float4* a4 = reinterpret_cast<const float4*>(mu_subj) + (size_t)p * (KK * DD / 4);
    const float4* b4 = reinterpret_cast<const float4*>(mu_pop);
    for (int o = threadIdx.x; o < 320; o += 256) {
      float4 a = a4[o], bb = b4[o];
      float d0 = a.x - bb.x, d1 = a.y - bb.y, d2 = a.z - bb.z, d3 = a.w - bb.w;
      s += d0 * d0 + d1 * d1 + d2 * d2 + d3 * d3;
    }
  }
  s = wave_sum(s);
  __shared__ float red[4];
  if ((threadIdx.x & 63) == 0) red[threadIdx.x >> 6] = s;
  __syncthreads();
  if (threadIdx.x == 0) *outp = red[0] + red[1] + red[2] + red[3];
}

// ---- K4: reduce all partials, compute n_unique, combine ----
__global__ __launch_bounds__(256) void k4_final(const int* __restrict__ sids,
                                                const float* __restrict__ ws,
                                                float* __restrict__ out) {
  int tid = threadIdx.x;
  __shared__ float nuniq;
  if (tid < 64) {
    int found = 0;
    for (int b2 = 0; b2 < BB; ++b2) found |= (sids[b2] == tid) ? 1 : 0;
    unsigned long long bal = __ballot(found != 0);
    if (tid == 0) nuniq = (float)__popcll(bal);
  }
  __syncthreads();
  float scale = nuniq / 64.0f;

  float a = 0.f;
  for (int i = tid; i < 2048; i += 256) a += ws[WS_PART2 + i];
  float lr = 0.f;
  for (int i = tid; i < 1600; i += 256) lr += ws[WS_PART3L + i];
  float mr = 0.f;
  if (tid < 64) mr = ws[WS_PART3M + tid];

  float v = a / 32768.0f + scale * 0.05f * (lr + mr);
  v = wave_sum(v);
  __shared__ float red[4];
  if ((tid & 63) == 0) red[tid >> 6] = v;
  __syncthreads();
  if (tid == 0) out[0] = red[0] + red[1] + red[2] + red[3];
}

extern "C" void kernel_launch(void* const* d_in, const int* in_sizes, int n_in,
                              void* d_out, int out_size, void* d_ws, size_t ws_size,
                              hipStream_t stream) {
  const float* x       = (const float*)d_in[0];
  const float* mu_pop  = (const float*)d_in[1];
  const float* L_pop   = (const float*)d_in[2];
  const float* mu_subj = (const float*)d_in[3];
  const float* L_subj  = (const float*)d_in[4];
  const float* gamma   = (const float*)d_in[5];
  const int*   sids    = (const int*)d_in[6];
  float* out = (float*)d_out;
  float* ws  = (float*)d_ws;

  hipLaunchKernelGGL(kx_cast, dim3(BB * 64), dim3(128), 0, stream, x, ws);
  hipLaunchKernelGGL(kg_t, dim3(TTOT / 256, BB), dim3(256), 0, stream, gamma, ws);
  hipLaunchKernelGGL(k1_inv, dim3(KK, BB), dim3(128), 0, stream, L_subj, mu_subj, sids, ws);
  hipLaunchKernelGGL(k2_mfma, dim3(KK, TTOT / 256, BB), dim3(256), 0, stream,
                     ws, ws + WS_PART2);
  hipLaunchKernelGGL(k3_reg, dim3(26, PP), dim3(256), 0, stream,
                     L_subj, L_pop, mu_subj, mu_pop, sids, ws);
  hipLaunchKernelGGL(k4_final, dim3(1), dim3(256), 0, stream, sids, ws, out);
}

// Round 16
// 49.127 us; speedup vs baseline: 1.8582x; 1.2118x over previous
//
#include <hip/hip_runtime.h>
#include <hip/hip_bf16.h>
#include <math.h>

#define BB 32
#define TTOT 1024
#define KK 16
#define DD 80
#define PP 64

// workspace layout (float offsets)
#define WS_DCONST 128      // 512
#define WS_CVEC   1024     // 512*80 -> 41984
#define WS_PART2  41984    // 2048 -> 44032
#define WS_PART3L 44032    // 1600 -> 45632
#define WS_PART3M 45632    // 64 -> 45696
#define WS_GAMT   46080    // gamma^T fp32 [32][16][1024] = 524288 -> 570368
#define WS_XBF16  570368   // X frag-major bf16 -> 2,143,232
#define WS_MINVB  2143232  // Minv frag-major bf16 -> 4,109,312 (16.4 MB)

typedef short bf16x8 __attribute__((ext_vector_type(8)));
typedef float f32x4 __attribute__((ext_vector_type(4)));

__device__ __forceinline__ float wave_sum(float v) {
#pragma unroll
  for (int o = 32; o > 0; o >>= 1) v += __shfl_down(v, o);
  return v;
}

__device__ __forceinline__ unsigned short f2bf(float f) {
  __hip_bfloat16 h = __float2bfloat16(f);
  return *reinterpret_cast<unsigned short*>(&h);
}

__device__ __forceinline__ bf16x8 pack8(float4 a, float4 b) {
  bf16x8 r;
  r[0] = (short)f2bf(a.x); r[1] = (short)f2bf(a.y);
  r[2] = (short)f2bf(a.z); r[3] = (short)f2bf(a.w);
  r[4] = (short)f2bf(b.x); r[5] = (short)f2bf(b.y);
  r[6] = (short)f2bf(b.z); r[7] = (short)f2bf(b.w);
  return r;
}

struct SmKx { float Lx[2][16][84]; };
struct SmKg { float tile[256][17]; };
struct SmK1 {
  float ys[DD * 81 + 64];
  float dinv[DD * 20];
  float Ls5[5][16][17];
  float lgd[DD];
  float rt[4][16 * 17];
};

// ---- PREP: kx_cast (blocks 0-1023, 2 groups each) + kg_t (1024-1151) +
//            k1_inv (1152-1663). Independent roles run concurrently: one
//            launch instead of three (R15: launch gaps + serial ramps were
//            the cost, not any single kernel).
__global__ __launch_bounds__(256, 1) void k_prep(const float* __restrict__ x,
                                                 const float* __restrict__ gamma,
                                                 const float* __restrict__ L_subj,
                                                 const float* __restrict__ mu_subj,
                                                 const int* __restrict__ sids,
                                                 float* __restrict__ ws) {
  __shared__ union { SmKx kx; SmKg kg; SmK1 k1; } sm;
  const int bid = blockIdx.x;
  const int tid = threadIdx.x;

  if (bid < 1024) {
    // ---- role KX: x -> bf16 B-fragment-major; half-block per 16-t group
    const int h = tid >> 7, t = tid & 127;
    const int g = bid * 2 + h;
    float(&Lx)[16][84] = sm.kx.Lx[h];
    const float* src = x + (size_t)g * 1280;
    for (int i2 = t; i2 < 320; i2 += 128) {
      float4 v = reinterpret_cast<const float4*>(src)[i2];
      int row = i2 / 20, c4 = (i2 % 20) * 4;
      *reinterpret_cast<float4*>(&Lx[row][c4]) = v;
    }
    __syncthreads();
    __hip_bfloat16* Xf = (__hip_bfloat16*)(ws + WS_XBF16) + (size_t)g * 1536;
    for (int s = t; s < 192; s += 128) {
      int c = s >> 6, l = s & 63, lg2 = (l >> 4), lr2 = l & 15;
      int col0 = c * 32 + lg2 * 8;
      bf16x8 v = {};
      if (col0 < DD) {
#pragma unroll
        for (int jj = 0; jj < 8; ++jj) v[jj] = (short)f2bf(Lx[lr2][col0 + jj]);
      }
      *reinterpret_cast<bf16x8*>(Xf + s * 8) = v;
    }
    return;
  }

  if (bid < 1152) {
    // ---- role KG: gamma [b][t][k] -> [b][k][t]
    const int idx0 = bid - 1024;
    const int tc = idx0 & 3, b = idx0 >> 2;
    const float* src = gamma + ((size_t)b * TTOT + tc * 256) * KK;
#pragma unroll
    for (int q = 0; q < 16; ++q) {
      int i2 = q * 256 + tid;
      sm.kg.tile[i2 >> 4][i2 & 15] = src[i2];
    }
    __syncthreads();
    float* dst = ws + WS_GAMT + (size_t)b * KK * TTOT;
#pragma unroll
    for (int q = 0; q < 16; ++q) {
      int i2 = q * 256 + tid;
      int kk = i2 >> 8, tl = i2 & 255;
      dst[kk * TTOT + tc * 256 + tl] = sm.kg.tile[tl][kk];
    }
    return;
  }

  // ---- role K1: triangular inverse via MFMA block recursion
  const int idx = bid - 1152;
  const int k = idx & 15, b = idx >> 4;
  const int p = sids[b];
  const float* Lg = L_subj + ((size_t)(p * KK + k)) * DD * DD;
  const float* mug = mu_subj + (size_t)(p * KK + k) * DD;
  const int bk = b * KK + k;

  const int w = tid >> 6, l = tid & 63;
  const int lr = l & 15, lg = l >> 4;

  // stage diagonal blocks + zero-init ys (upper blocks must read as 0)
  for (int i2 = tid; i2 < 5 * 256; i2 += 256) {
    int blk = i2 >> 8, ii = (i2 >> 4) & 15, mm = i2 & 15;
    sm.k1.Ls5[blk][ii][mm] = Lg[(blk * 16 + ii) * DD + blk * 16 + mm];
  }
  for (int i2 = tid; i2 < DD * 81 + 64; i2 += 256) sm.k1.ys[i2] = 0.f;
  __syncthreads();

  // Phase 1: invert diagonal 16x16 blocks from LDS (tid<80)
  if (tid < DD) {
    const int ci5 = tid >> 4, jj = tid & 15;
    float rd[16];
#pragma unroll
    for (int ii = 0; ii < 16; ++ii) rd[ii] = 1.0f / sm.k1.Ls5[ci5][ii][ii];
    float yc[16];
#pragma unroll
    for (int ii = 0; ii < 16; ++ii) {
      float v = (ii == jj) ? 1.0f : 0.0f;
#pragma unroll
      for (int mm = 0; mm < 16; ++mm)
        if (mm < ii) v = fmaf(-sm.k1.Ls5[ci5][ii][mm], yc[mm], v);
      yc[ii] = v * rd[ii];
    }
#pragma unroll
    for (int ii = 0; ii < 16; ++ii) sm.k1.dinv[(ci5 * 16 + ii) * 20 + jj] = yc[ii];
    sm.k1.lgd[tid] = logf(sm.k1.Ls5[ci5][jj][jj]);
  }
  __syncthreads();

  // Phase 2: 4-wave column ownership (w0:{0} w1:{1} w2:{2} w3:{3,4}),
  // lower-triangular tiles only, diagonal = Dinv copy. No barriers inside.
  float* rtw = sm.k1.rt[w];
  for (int nt = w; nt < 5; nt += (w == 3) ? 1 : 5) {
    const int col = nt * 16 + lr;
    if (lg == 0) {
#pragma unroll
      for (int ii = 0; ii < 16; ++ii)
        sm.k1.ys[(nt * 16 + ii) * 81 + col] = sm.k1.dinv[(nt * 16 + ii) * 20 + lr];
    }
    for (int ci = nt + 1; ci < 5; ++ci) {
      const int r0 = ci * 16;
      const int ktot = ci * 16;
      const int nch = (ci + 1) >> 1;

      bf16x8 aL0 = {}, aL1 = {};
      if (nch > 0 && (lg * 8) < ktot) {
        const float* src = &Lg[(r0 + lr) * DD + lg * 8];
        aL0 = pack8(*reinterpret_cast<const float4*>(src),
                    *reinterpret_cast<const float4*>(src + 4));
      }
      if (nch > 1 && (32 + lg * 8) < ktot) {
        const float* src = &Lg[(r0 + lr) * DD + 32 + lg * 8];
        aL1 = pack8(*reinterpret_cast<const float4*>(src),
                    *reinterpret_cast<const float4*>(src + 4));
      }
      bf16x8 aD = {};
      if (lg < 2) {
        const float* src = &sm.k1.dinv[(r0 + lr) * 20 + lg * 8];
        aD = pack8(*reinterpret_cast<const float4*>(src),
                   *reinterpret_cast<const float4*>(src + 4));
      }

      f32x4 S = {};
      if (nch > 0) {
        bf16x8 b0 = {};
        if ((lg * 8) < ktot) {
          const int kb = lg * 8;
#pragma unroll
          for (int jj = 0; jj < 8; ++jj)
            b0[jj] = (short)f2bf(sm.k1.ys[(kb + jj) * 81 + col]);
        }
        S = __builtin_amdgcn_mfma_f32_16x16x32_bf16(aL0, b0, S, 0, 0, 0);
      }
      if (nch > 1) {
        bf16x8 b1 = {};
        if ((32 + lg * 8) < ktot) {
          const int kb = 32 + lg * 8;
#pragma unroll
          for (int jj = 0; jj < 8; ++jj)
            b1[jj] = (short)f2bf(sm.k1.ys[(kb + jj) * 81 + col]);
        }
        S = __builtin_amdgcn_mfma_f32_16x16x32_bf16(aL1, b1, S, 0, 0, 0);
      }
      // R = -S (off-diagonal E block is zero); bounce C-layout -> B-layout
#pragma unroll
      for (int r = 0; r < 4; ++r) rtw[(lg * 4 + r) * 17 + lr] = -S[r];
      bf16x8 bR = {};
      if (lg < 2) {
#pragma unroll
        for (int jj = 0; jj < 8; ++jj)
          bR[jj] = (short)f2bf(rtw[(lg * 8 + jj) * 17 + lr]);
      }
      f32x4 Y = {};
      Y = __builtin_amdgcn_mfma_f32_16x16x32_bf16(aD, bR, Y, 0, 0, 0);
#pragma unroll
      for (int r = 0; r < 4; ++r) sm.k1.ys[(r0 + lg * 4 + r) * 81 + col] = Y[r];
    }
  }
  __syncthreads();

  // Minv write in A-fragment-major layout (zeros in K-pad slots)
  __hip_bfloat16* Mf = (__hip_bfloat16*)(ws + WS_MINVB) + (size_t)bk * 7680;
  for (int s = tid; s < 960; s += 256) {
    int mtc = s >> 6, l2 = s & 63;
    int row = (mtc / 3) * 16 + (l2 & 15);
    int col0 = (mtc % 3) * 32 + (l2 >> 4) * 8;
    bf16x8 v = {};
    if (col0 < DD) {
#pragma unroll
      for (int jj = 0; jj < 8; ++jj) v[jj] = (short)f2bf(sm.k1.ys[row * 81 + col0 + jj]);
    }
    *reinterpret_cast<bf16x8*>(Mf + s * 8) = v;
  }

  if (tid < DD) {
    int i = tid;
    float ci = 0.f;
#pragma unroll 8
    for (int jj = 0; jj < DD; ++jj) ci = fmaf(sm.k1.ys[i * 81 + jj], mug[jj], ci);
    ws[WS_CVEC + bk * DD + i] = ci;
  }
  if (tid == 0) {
    float s = 0.f;
    for (int i = 0; i < DD; ++i) s += sm.k1.lgd[i];
    ws[WS_DCONST + bk] = (float)(0.5 * 80.0 * 1.8378770664093453) + s;
  }
}

// ---- MAIN: k2_mfma (blocks 0-2047) + k3 regularizers (2048-3711) ----
__global__ __launch_bounds__(256) void k_main(const float* __restrict__ ws_ro,
                                              const float* __restrict__ L_subj,
                                              const float* __restrict__ L_pop,
                                              const float* __restrict__ mu_subj,
                                              const float* __restrict__ mu_pop,
                                              const int* __restrict__ sids,
                                              float* __restrict__ ws) {
  __shared__ float red[4];
  const int bid = blockIdx.x;

  if (bid < 2048) {
    // ---- role K2
    const int k = bid & 15, tt = (bid >> 4) & 3, b = bid >> 6;
    const int w = threadIdx.x >> 6, l = threadIdx.x & 63;
    const int lg = l >> 4, lr = l & 15;
    const int bk = b * KK + k;

    const __hip_bfloat16* Mf = (const __hip_bfloat16*)(ws_ro + WS_MINVB) + (size_t)bk * 7680;
    const __hip_bfloat16* Xf = (const __hip_bfloat16*)(ws_ro + WS_XBF16);
    const float* gamt = ws_ro + WS_GAMT + ((size_t)b * KK + k) * TTOT;
    const float* cc = ws_ro + WS_CVEC + bk * DD;
    const float dconst = ws_ro[WS_DCONST + bk];

    const int t0 = tt * 256 + w * 64;
    const int tg0 = tt * 16 + w * 4;

    f32x4 accf[5][4] = {};
#pragma unroll
    for (int c = 0; c < 3; ++c) {
      bf16x8 af[5], bf[4];
#pragma unroll
      for (int mt = 0; mt < 5; ++mt)
        af[mt] = *(const bf16x8*)(Mf + ((mt * 3 + c) * 64 + l) * 8);
#pragma unroll
      for (int nf = 0; nf < 4; ++nf)
        bf[nf] = *(const bf16x8*)(Xf + ((size_t)(b * 64 + tg0 + nf) * 192 + c * 64 + l) * 8);
#pragma unroll
      for (int mt = 0; mt < 5; ++mt)
#pragma unroll
        for (int nf = 0; nf < 4; ++nf)
          accf[mt][nf] = __builtin_amdgcn_mfma_f32_16x16x32_bf16(af[mt], bf[nf], accf[mt][nf], 0, 0, 0);
    }

    float c_r[5][4];
#pragma unroll
    for (int mt = 0; mt < 5; ++mt)
#pragma unroll
      for (int r = 0; r < 4; ++r)
        c_r[mt][r] = cc[mt * 16 + lg * 4 + r];

    float v = 0.f;
#pragma unroll
    for (int nf = 0; nf < 4; ++nf) {
      float s = 0.f;
#pragma unroll
      for (int mt = 0; mt < 5; ++mt)
#pragma unroll
        for (int r = 0; r < 4; ++r) {
          float z = accf[mt][nf][r] - c_r[mt][r];
          s = fmaf(z, z, s);
        }
      s += __shfl_xor(s, 16);
      s += __shfl_xor(s, 32);
      float g = 0.f;
      int t = t0 + nf * 16 + lr;
      if (l < 16) g = gamt[t];
      v = fmaf(g, dconst + 0.5f * s, v);
    }
    v = wave_sum(v);
    if (l == 0) red[w] = v;
    __syncthreads();
    if (threadIdx.x == 0)
      ws[WS_PART2 + (b * 4 + tt) * KK + k] = red[0] + red[1] + red[2] + red[3];
    return;
  }

  // ---- role K3: L reg (chunk 0-24) + mu reg (chunk 25)
  const int idx = bid - 2048;
  const int p = idx / 26, chunk = idx - p * 26;
  int found = 0;
  for (int b2 = 0; b2 < BB; ++b2) found |= (sids[b2] == p) ? 1 : 0;
  float* outp = (chunk < 25) ? &ws[WS_PART3L + p * 25 + chunk] : &ws[WS_PART3M + p];
  if (!found) {
    if (threadIdx.x == 0) *outp = 0.f;
    return;
  }
  float s = 0.f;
  if (chunk < 25) {
    const float4* a4 = reinterpret_cast<const float4*>(L_subj) + (size_t)p * (KK * DD * DD / 4);
    const float4* b4 = reinterpret_cast<const float4*>(L_pop);
#pragma unroll
    for (int q = 0; q < 4; ++q) {
      int o = chunk * 1024 + q * 256 + threadIdx.x;
      float4 a = a4[o], bb = b4[o];
      float d0 = a.x - bb.x, d1 = a.y - bb.y, d2 = a.z - bb.z, d3 = a.w - bb.w;
      s += d0 * d0 + d1 * d1 + d2 * d2 + d3 * d3;
    }
  } else {
    const float4* a4 = reinterpret_cast<const float4*>(mu_subj) + (size_t)p * (KK * DD / 4);
    const float4* b4 = reinterpret_cast<const float4*>(mu_pop);
    for (int o = threadIdx.x; o < 320; o += 256) {
      float4 a = a4[o], bb = b4[o];
      float d0 = a.x - bb.x, d1 = a.y - bb.y, d2 = a.z - bb.z, d3 = a.w - bb.w;
      s += d0 * d0 + d1 * d1 + d2 * d2 + d3 * d3;
    }
  }
  s = wave_sum(s);
  if ((threadIdx.x & 63) == 0) red[threadIdx.x >> 6] = s;
  __syncthreads();
  if (threadIdx.x == 0) *outp = red[0] + red[1] + red[2] + red[3];
}

// ---- K4: reduce all partials, compute n_unique, combine ----
__global__ __launch_bounds__(256) void k4_final(const int* __restrict__ sids,
                                                const float* __restrict__ ws,
                                                float* __restrict__ out) {
  int tid = threadIdx.x;
  __shared__ float nuniq;
  if (tid < 64) {
    int found = 0;
    for (int b2 = 0; b2 < BB; ++b2) found |= (sids[b2] == tid) ? 1 : 0;
    unsigned long long bal = __ballot(found != 0);
    if (tid == 0) nuniq = (float)__popcll(bal);
  }
  __syncthreads();
  float scale = nuniq / 64.0f;

  float a = 0.f;
  for (int i = tid; i < 2048; i += 256) a += ws[WS_PART2 + i];
  float lr = 0.f;
  for (int i = tid; i < 1600; i += 256) lr += ws[WS_PART3L + i];
  float mr = 0.f;
  if (tid < 64) mr = ws[WS_PART3M + tid];

  float v = a / 32768.0f + scale * 0.05f * (lr + mr);
  v = wave_sum(v);
  __shared__ float red[4];
  if ((tid & 63) == 0) red[tid >> 6] = v;
  __syncthreads();
  if (tid == 0) out[0] = red[0] + red[1] + red[2] + red[3];
}

extern "C" void kernel_launch(void* const* d_in, const int* in_sizes, int n_in,
                              void* d_out, int out_size, void* d_ws, size_t ws_size,
                              hipStream_t stream) {
  const float* x       = (const float*)d_in[0];
  const float* mu_pop  = (const float*)d_in[1];
  const float* L_pop   = (const float*)d_in[2];
  const float* mu_subj = (const float*)d_in[3];
  const float* L_subj  = (const float*)d_in[4];
  const float* gamma   = (const float*)d_in[5];
  const int*   sids    = (const int*)d_in[6];
  float* out = (float*)d_out;
  float* ws  = (float*)d_ws;

  hipLaunchKernelGGL(k_prep, dim3(1664), dim3(256), 0, stream,
                     x, gamma, L_subj, mu_subj, sids, ws);
  hipLaunchKernelGGL(k_main, dim3(3712), dim3(256), 0, stream,
                     ws, L_subj, L_pop, mu_subj, mu_pop, sids, ws);
  hipLaunchKernelGGL(k4_final, dim3(1), dim3(256), 0, stream, sids, ws, out);
}